// Round 5
// baseline (275.907 us; speedup 1.0000x reference)
//
#include <hip/hip_runtime.h>

#define D_MODEL 1024
#define SEQ 2048
#define BATCH 4
#define NHEADS 16
#define HDK 64
#define MTOT (BATCH * SEQ)  // 8192
#define NT (SEQ / 64)       // 32 KV tiles

typedef __attribute__((ext_vector_type(8))) _Float16 f16x8;
typedef __attribute__((ext_vector_type(2))) __fp16 pk16x2;
typedef __attribute__((ext_vector_type(4))) float f32x4;

__device__ inline unsigned short f2h_bits(float f) {
  _Float16 h = (_Float16)f;
  union { _Float16 h; unsigned short u; } c;
  c.h = h;
  return c.u;
}

__device__ inline unsigned pk2(float a, float b) {
  union { pk16x2 h; unsigned u; } c;
  c.h = __builtin_amdgcn_cvt_pkrtz(a, b);  // lo=a, hi=b
  return c.u;
}

// global -> LDS direct async copy, 16B per lane. LDS dest must be linear
// (wave-uniform base + lane*16); swizzle is pre-applied on the GLOBAL side.
typedef __attribute__((address_space(3))) unsigned int lds_u32_t;
typedef __attribute__((address_space(1))) const unsigned int glb_u32_t;
__device__ __forceinline__ void gll16(const void* g, void* l) {
  __builtin_amdgcn_global_load_lds((glb_u32_t*)g, (lds_u32_t*)l, 16, 0, 0);
}

// ---------------------------------------------------------------------------
// Weight transpose + fp32->f16 convert, PRE-SWIZZLED for global_load_lds:
// within each 64-col k-chunk, 8-elem group c8 is stored at slot c8^(n&7).
// ---------------------------------------------------------------------------
__global__ __launch_bounds__(256) void wtrans_kernel(
    const float* __restrict__ W0, const float* __restrict__ W1,
    const float* __restrict__ W2, const float* __restrict__ W3,
    unsigned short* __restrict__ WT) {
  __shared__ float tile[64][65];
  const float* W = blockIdx.z == 0 ? W0 : blockIdx.z == 1 ? W1
                  : blockIdx.z == 2 ? W2 : W3;
  unsigned short* out = WT + (size_t)blockIdx.z * D_MODEL * D_MODEL;
  const int k0 = blockIdx.x * 64, n0 = blockIdx.y * 64;
  const int t = threadIdx.x;
#pragma unroll
  for (int i = 0; i < 16; ++i) {
    int e = t + i * 256;
    int r = e >> 6, c = e & 63;
    tile[r][c] = W[(size_t)(k0 + r) * D_MODEL + n0 + c];
  }
  __syncthreads();
#pragma unroll
  for (int i = 0; i < 16; ++i) {
    int e = t + i * 256;
    int r = e >> 6, c = e & 63;  // r = n-local, c = k-local
    int slot = (c >> 3) ^ (r & 7);
    out[(size_t)(n0 + r) * D_MODEL + k0 + slot * 8 + (c & 7)] =
        f2h_bits(tile[c][r]);
  }
}

// ---------------------------------------------------------------------------
// GEMM: C[8192][1024] = A @ W + bias. B (WT) is transposed + pre-swizzled,
// staged via global_load_lds into linear LDS (net effect: swizzled tile).
// A_MODE: 0 = fp32 reg-staged (+cvt, swizzled ds_write), 1 = f16 pre-swizzled
// source via global_load_lds.
// OUT_MODE: 0 = f16 linear (QP), 1 = f32 linear (final out),
//           2 = f16 head-transposed + key-swizzled (VPT),
//           3 = f16 linear rows + col-swizzled (KP / CTX).
// Grid: 1-D 512, by = id&7 (XCD owns one B panel), bx = id>>3.
// ---------------------------------------------------------------------------
template <int A_MODE, int OUT_MODE>
__global__ __launch_bounds__(256) void gemm_kernel(
    const void* __restrict__ Aptr, const unsigned short* __restrict__ Bt,
    const float* __restrict__ bias, void* __restrict__ Cptr) {
  __shared__ unsigned short As[128 * 64];
  __shared__ unsigned short Bs[128 * 64];
  const int t = threadIdx.x;
  const int lane = t & 63, w = t >> 6;
  const int lo16 = lane & 15, g = lane >> 4;
  const int wr = w >> 1, wc = w & 1;
  const int bx = blockIdx.x >> 3, by = blockIdx.x & 7;
  const int m0 = bx * 128, n0 = by * 128;

  f32x4 acc[4][4] = {};

  const unsigned short* bgb =
      Bt + (size_t)(n0 + (t >> 3)) * D_MODEL + (t & 7) * 8;
  const float* agf = nullptr;
  const unsigned short* agh = nullptr;
  if constexpr (A_MODE == 0)
    agf = (const float*)Aptr + (size_t)(m0 + (t >> 4)) * D_MODEL + (t & 15) * 4;
  else
    agh = (const unsigned short*)Aptr + (size_t)(m0 + (t >> 3)) * D_MODEL +
          (t & 7) * 8;

  for (int kt = 0; kt < D_MODEL / 64; ++kt) {
    if constexpr (A_MODE == 0) {
#pragma unroll
      for (int i = 0; i < 8; ++i) {
        int row = (t >> 4) + i * 16, kq = (t & 15) * 4;
        float4 vv = *reinterpret_cast<const float4*>(agf + (size_t)i * 16 * D_MODEL);
        int slot = (kq >> 3) ^ (row & 7);
        uint2 pp;
        pp.x = pk2(vv.x, vv.y);
        pp.y = pk2(vv.z, vv.w);
        *reinterpret_cast<uint2*>(&As[row * 64 + slot * 8 + (kq & 7)]) = pp;
      }
      agf += 64;
    } else {
#pragma unroll
      for (int i = 0; i < 4; ++i)
        gll16(agh + (size_t)i * 32 * D_MODEL, &As[(size_t)(i * 256 + t) * 8]);
      agh += 64;
    }
#pragma unroll
    for (int i = 0; i < 4; ++i)
      gll16(bgb + (size_t)i * 32 * D_MODEL, &Bs[(size_t)(i * 256 + t) * 8]);
    bgb += 64;
    __syncthreads();

#pragma unroll
    for (int kk = 0; kk < 2; ++kk) {
      f16x8 af[4], bfr[4];
#pragma unroll
      for (int m = 0; m < 4; ++m) {
        int row = wr * 64 + m * 16 + lo16;
        int slot = (kk * 4 + g) ^ (row & 7);
        af[m] = *reinterpret_cast<const f16x8*>(&As[row * 64 + slot * 8]);
      }
#pragma unroll
      for (int n = 0; n < 4; ++n) {
        int row = wc * 64 + n * 16 + lo16;
        int slot = (kk * 4 + g) ^ (row & 7);
        bfr[n] = *reinterpret_cast<const f16x8*>(&Bs[row * 64 + slot * 8]);
      }
#pragma unroll
      for (int m = 0; m < 4; ++m)
#pragma unroll
        for (int n = 0; n < 4; ++n)
          acc[m][n] = __builtin_amdgcn_mfma_f32_16x16x32_f16(af[m], bfr[n],
                                                             acc[m][n], 0, 0, 0);
    }
    __syncthreads();
  }

#pragma unroll
  for (int m = 0; m < 4; ++m) {
#pragma unroll
    for (int n = 0; n < 4; ++n) {
      int col = n0 + wc * 64 + n * 16 + lo16;
      float bv = bias[col];
      if constexpr (OUT_MODE == 2) {
        // VPT[b][h][dk][s], key-dim pre-swizzled by dk&7
        int hh = col >> 6, dk = col & 63;
        int r = m0 + wr * 64 + m * 16 + g * 4;
        int bb = r >> 11, ss = r & 2047;
        int ssw = (ss & ~63) + ((((ss >> 3) & 7) ^ (dk & 7)) << 3) + (ss & 7);
        ushort4 pkv;
        pkv.x = f2h_bits(acc[m][n][0] + bv);
        pkv.y = f2h_bits(acc[m][n][1] + bv);
        pkv.z = f2h_bits(acc[m][n][2] + bv);
        pkv.w = f2h_bits(acc[m][n][3] + bv);
        *reinterpret_cast<ushort4*>(
            (unsigned short*)Cptr +
            (((size_t)bb * NHEADS + hh) * HDK + dk) * SEQ + ssw) = pkv;
      } else if constexpr (OUT_MODE == 3) {
        // f16, columns pre-swizzled within 64-chunks by row&7
        int colbase = col & ~63, c8 = (col >> 3) & 7, c1 = col & 7;
#pragma unroll
        for (int j = 0; j < 4; ++j) {
          int row = m0 + wr * 64 + m * 16 + g * 4 + j;
          int colp = colbase + ((c8 ^ ((g * 4 + j) & 7)) << 3) + c1;
          ((unsigned short*)Cptr)[(size_t)row * D_MODEL + colp] =
              f2h_bits(acc[m][n][j] + bv);
        }
      } else {
#pragma unroll
        for (int j = 0; j < 4; ++j) {
          int row = m0 + wr * 64 + m * 16 + g * 4 + j;
          float val = acc[m][n][j] + bv;
          if constexpr (OUT_MODE == 1) {
            ((float*)Cptr)[(size_t)row * D_MODEL + col] = val;
          } else {
            ((unsigned short*)Cptr)[(size_t)row * D_MODEL + col] = f2h_bits(val);
          }
        }
      }
    }
  }
}

// ---------------------------------------------------------------------------
// Flash attention: swapped QK^T, in-register P redistribution, fixed m=0
// softmax, deferred lsum. NEW: 3-buffer LDS with global_load_lds staging
// (pre-swizzled KP/VPT) and a 2-stage score pipeline: QKT(t+1) is issued
// before softmax/PV(t), hiding MFMA latency under the VALU phase.
// Grid: 1-D 1024, bh = id&63 (XCD L2 holds its 8 (b,h) K/V sets).
// ---------------------------------------------------------------------------
__global__ __launch_bounds__(256, 3) void attn_kernel(
    const unsigned short* __restrict__ QP, const unsigned short* __restrict__ KP,
    const unsigned short* __restrict__ VPT, unsigned short* __restrict__ CTX) {
  __shared__ unsigned short Kb[3][64 * 64];
  __shared__ unsigned short Vb[3][64 * 64];
  const int t = threadIdx.x;
  const int lane = t & 63, w = t >> 6;
  const int lo16 = lane & 15, g = lane >> 4;
  const int bh = blockIdx.x & 63, qt = blockIdx.x >> 6;
  const int b = bh >> 4, h = bh & 15;
  const int q0 = qt * 128;
  const size_t rowbase = (size_t)b * SEQ;

  // Q as B-operand fragments, pre-scaled by 0.125 * log2(e) (exp2 domain)
  f16x8 qf[2][2];
#pragma unroll
  for (int nQ = 0; nQ < 2; ++nQ)
#pragma unroll
    for (int kk = 0; kk < 2; ++kk) {
      qf[nQ][kk] = *reinterpret_cast<const f16x8*>(
          QP + (rowbase + q0 + w * 32 + nQ * 16 + lo16) * D_MODEL + h * 64 +
          kk * 32 + g * 8);
      qf[nQ][kk] *= (_Float16)0.18033688f;
    }

  f32x4 o_acc[2][4] = {};
  float lsum[2] = {0.f, 0.f};

  // Per-thread staging bases (linear LDS <- pre-swizzled global)
  const unsigned short* kgb =
      KP + (rowbase + (t >> 3)) * D_MODEL + h * 64 + (t & 7) * 8;
  const unsigned short* vgb =
      VPT + ((size_t)bh * HDK + (t >> 3)) * SEQ + (t & 7) * 8;

  // Prologue: stage tiles 0 and 1
#pragma unroll
  for (int i = 0; i < 2; ++i) {
    gll16(kgb + (size_t)i * 32 * D_MODEL, &Kb[0][(size_t)(i * 256 + t) * 8]);
    gll16(vgb + (size_t)i * 32 * SEQ, &Vb[0][(size_t)(i * 256 + t) * 8]);
  }
  kgb += (size_t)64 * D_MODEL; vgb += 64;
#pragma unroll
  for (int i = 0; i < 2; ++i) {
    gll16(kgb + (size_t)i * 32 * D_MODEL, &Kb[1][(size_t)(i * 256 + t) * 8]);
    gll16(vgb + (size_t)i * 32 * SEQ, &Vb[1][(size_t)(i * 256 + t) * 8]);
  }
  kgb += (size_t)64 * D_MODEL; vgb += 64;  // now at tile 2
  __syncthreads();

  const bool evn = ((g & 1) == 0);
  const bool lowp = (g < 2);
  const bool isg0 = (g == 0), isg3 = (g == 3);

  f32x4 sA[4][2], sB[4][2];

  auto qkt = [&](const unsigned short* Ksh, f32x4 (&sd)[4][2]) {
#pragma unroll
    for (int mK = 0; mK < 4; ++mK)
#pragma unroll
      for (int nQ = 0; nQ < 2; ++nQ) sd[mK][nQ] = f32x4{0.f, 0.f, 0.f, 0.f};
#pragma unroll
    for (int kk = 0; kk < 2; ++kk) {
      f16x8 kf[4];
#pragma unroll
      for (int mK = 0; mK < 4; ++mK)
        kf[mK] = *reinterpret_cast<const f16x8*>(
            &Ksh[(mK * 16 + lo16) * 64 + (((kk * 4 + g) ^ (lo16 & 7)) * 8)]);
#pragma unroll
      for (int mK = 0; mK < 4; ++mK)
#pragma unroll
        for (int nQ = 0; nQ < 2; ++nQ)
          sd[mK][nQ] = __builtin_amdgcn_mfma_f32_16x16x32_f16(
              kf[mK], qf[nQ][kk], sd[mK][nQ], 0, 0, 0);
    }
  };

  auto body = [&](int tl, f32x4 (&scur)[4][2], f32x4 (&snxt)[4][2], int iv,
                  int ik, int iw) {
    // 1. stage tile tl+2 into write buffer (async, lands by end-of-iter drain)
    if (tl + 2 < NT) {
#pragma unroll
      for (int i = 0; i < 2; ++i) {
        gll16(kgb + (size_t)i * 32 * D_MODEL,
              &Kb[iw][(size_t)(i * 256 + t) * 8]);
        gll16(vgb + (size_t)i * 32 * SEQ, &Vb[iw][(size_t)(i * 256 + t) * 8]);
      }
      kgb += (size_t)64 * D_MODEL; vgb += 64;
    }
    // 2. QKT for tile tl+1 (independent of scur's softmax below)
    if (tl + 1 < NT) qkt(&Kb[ik][0], snxt);

    // 3. softmax numerator (fixed m=0) + lsum partials on scur
#pragma unroll
    for (int nQ = 0; nQ < 2; ++nQ) {
#pragma unroll
      for (int mK = 0; mK < 4; ++mK)
#pragma unroll
        for (int j = 0; j < 4; ++j)
          scur[mK][nQ][j] = __builtin_amdgcn_exp2f(scur[mK][nQ][j]);
      f32x4 sm = (scur[0][nQ] + scur[1][nQ]) + (scur[2][nQ] + scur[3][nQ]);
      lsum[nQ] += (sm[0] + sm[1]) + (sm[2] + sm[3]);
    }

    // 4. PV: redistribute P (C/D -> A-fragment) in registers, O += P V
    const unsigned short* Vsh = &Vb[iv][0];
#pragma unroll
    for (int kk = 0; kk < 2; ++kk) {
      f16x8 pf[2];
#pragma unroll
      for (int mA = 0; mA < 2; ++mA) {
        unsigned L0 = pk2(scur[2 * kk][mA][0], scur[2 * kk][mA][1]);
        unsigned L1 = pk2(scur[2 * kk][mA][2], scur[2 * kk][mA][3]);
        unsigned H0 = pk2(scur[2 * kk + 1][mA][0], scur[2 * kk + 1][mA][1]);
        unsigned H1 = pk2(scur[2 * kk + 1][mA][2], scur[2 * kk + 1][mA][3]);
        unsigned L0x = __shfl_xor(L0, 16), L1x = __shfl_xor(L1, 16);
        unsigned H0x = __shfl_xor(H0, 16), H1x = __shfl_xor(H1, 16);
        unsigned EL0 = evn ? L0 : L0x, EL1 = evn ? L1 : L1x;
        unsigned OL0 = evn ? L0x : L0, OL1 = evn ? L1x : L1;
        unsigned EH0 = evn ? H0 : H0x, EH1 = evn ? H1 : H1x;
        unsigned OH0 = evn ? H0x : H0, OH1 = evn ? H1x : H1;
        unsigned R0 = __shfl_xor(lowp ? EH0 : EL0, 32);
        unsigned R1 = __shfl_xor(lowp ? EH1 : EL1, 32);
        unsigned R2 = __shfl_xor(lowp ? OH0 : OL0, 32);
        unsigned R3 = __shfl_xor(lowp ? OH1 : OL1, 32);
        unsigned W0 = isg0 ? EL0 : (isg3 ? EH0 : R0);
        unsigned W1 = isg0 ? EL1 : (isg3 ? EH1 : R1);
        unsigned W2 = isg0 ? OL0 : (isg3 ? OH0 : R2);
        unsigned W3 = isg0 ? OL1 : (isg3 ? OH1 : R3);
        union { uint4 u; f16x8 h; } cv;
        cv.u = make_uint4(W0, W1, W2, W3);
        pf[mA] = cv.h;
      }
      f16x8 vf[4];
#pragma unroll
      for (int n4 = 0; n4 < 4; ++n4)
        vf[n4] = *reinterpret_cast<const f16x8*>(
            &Vsh[(n4 * 16 + lo16) * 64 + (((kk * 4 + g) ^ (lo16 & 7)) * 8)]);
#pragma unroll
      for (int mA = 0; mA < 2; ++mA)
#pragma unroll
        for (int n4 = 0; n4 < 4; ++n4)
          o_acc[mA][n4] = __builtin_amdgcn_mfma_f32_16x16x32_f16(
              pf[mA], vf[n4], o_acc[mA][n4], 0, 0, 0);
    }
    __syncthreads();
  };

  // Prologue QKT on tile 0
  qkt(&Kb[0][0], sA);

  int iv = 0, ik = 1, iw = 2;
  for (int tp = 0; tp < NT; tp += 2) {
    body(tp, sA, sB, iv, ik, iw);
    { int x = iv; iv = ik; ik = iw; iw = x; }
    body(tp + 1, sB, sA, iv, ik, iw);
    { int x = iv; iv = ik; ik = iw; iw = x; }
  }

  // Epilogue: deferred lsum reduce, normalize, store CTX pre-swizzled
#pragma unroll
  for (int nQ = 0; nQ < 2; ++nQ) {
    lsum[nQ] += __shfl_xor(lsum[nQ], 16);
    lsum[nQ] += __shfl_xor(lsum[nQ], 32);
  }
  float li[2][4];
#pragma unroll
  for (int mA = 0; mA < 2; ++mA)
#pragma unroll
    for (int j = 0; j < 4; ++j)
      li[mA][j] = 1.0f / __shfl(lsum[mA], g * 4 + j);
#pragma unroll
  for (int mA = 0; mA < 2; ++mA)
#pragma unroll
    for (int n4 = 0; n4 < 4; ++n4) {
      int c8 = ((n4 * 16 + lo16) >> 3) & 7, c1 = lo16 & 7;
#pragma unroll
      for (int j = 0; j < 4; ++j) {
        size_t row = rowbase + q0 + w * 32 + mA * 16 + g * 4 + j;
        int tok7 = (g * 4 + j) & 7;
        CTX[row * D_MODEL + h * 64 + ((c8 ^ tok7) << 3) + c1] =
            f2h_bits(o_acc[mA][n4][j] * li[mA][j]);
      }
    }
}

// ---------------------------------------------------------------------------
extern "C" void kernel_launch(void* const* d_in, const int* in_sizes, int n_in,
                              void* d_out, int out_size, void* d_ws,
                              size_t ws_size, hipStream_t stream) {
  (void)in_sizes; (void)n_in; (void)out_size; (void)ws_size;
  const float* q  = (const float*)d_in[0];
  const float* k  = (const float*)d_in[1];
  const float* v  = (const float*)d_in[2];
  const float* Wq = (const float*)d_in[3];
  const float* bq = (const float*)d_in[4];
  const float* Wk = (const float*)d_in[5];
  const float* bk = (const float*)d_in[6];
  const float* Wv = (const float*)d_in[7];
  const float* bv = (const float*)d_in[8];
  const float* Wo = (const float*)d_in[9];
  const float* bo = (const float*)d_in[10];

  // ws layout (f16): 4 transposed+pre-swizzled weights | QP | KP | VPT | CTX
  unsigned short* WT  = (unsigned short*)d_ws;
  unsigned short* QP  = WT + (size_t)4 * D_MODEL * D_MODEL;
  unsigned short* KP  = QP + (size_t)MTOT * D_MODEL;
  unsigned short* VPT = KP + (size_t)MTOT * D_MODEL;
  unsigned short* CTX = VPT + (size_t)MTOT * D_MODEL;

  wtrans_kernel<<<dim3(16, 16, 4), 256, 0, stream>>>(Wq, Wk, Wv, Wo, WT);

  // QP: linear f16 (mode 0); KP: col-swizzled (mode 3); VPT: transposed+swz (2)
  gemm_kernel<0, 0><<<512, 256, 0, stream>>>(
      q, WT + (size_t)0 * D_MODEL * D_MODEL, bq, QP);
  gemm_kernel<0, 3><<<512, 256, 0, stream>>>(
      k, WT + (size_t)1 * D_MODEL * D_MODEL, bk, KP);
  gemm_kernel<0, 2><<<512, 256, 0, stream>>>(
      v, WT + (size_t)2 * D_MODEL * D_MODEL, bv, VPT);

  attn_kernel<<<1024, 256, 0, stream>>>(QP, KP, VPT, CTX);

  // O-projection: A = CTX (f16, pre-swizzled -> global_load_lds), out fp32
  gemm_kernel<1, 1><<<512, 256, 0, stream>>>(
      CTX, WT + (size_t)3 * D_MODEL * D_MODEL, bo, d_out);
}